// Round 1
// baseline (80.639 us; speedup 1.0000x reference)
//
#include <hip/hip_runtime.h>
#include <hip/hip_bf16.h>
#include <stdint.h>

#define NB 4096
#define ND 1024

typedef __attribute__((ext_vector_type(8))) short bf16x8;
typedef __attribute__((ext_vector_type(4))) float f32x4;

// ---------------------------------------------------------------------------
// prep: row-normalize to bf16, compute m_i = sum(bf16(z)^2)/TAU, pack label key
// ---------------------------------------------------------------------------
__global__ __launch_bounds__(256) void prep_kernel(
    const float* __restrict__ emb, const int* __restrict__ labels,
    unsigned short* __restrict__ z, float* __restrict__ mvec, int* __restrict__ keys)
{
    const int row = blockIdx.x;
    const int t = threadIdx.x;
    const int lane = t & 63, wid = t >> 6;
    __shared__ float wred[4];

    const float4 e4 = ((const float4*)(emb + (size_t)row * ND))[t];
    float ss = e4.x*e4.x + e4.y*e4.y + e4.z*e4.z + e4.w*e4.w;
    #pragma unroll
    for (int o = 32; o > 0; o >>= 1) ss += __shfl_xor(ss, o);
    if (lane == 0) wred[wid] = ss;
    __syncthreads();
    ss = wred[0] + wred[1] + wred[2] + wred[3];

    const float inv = 1.0f / fmaxf(sqrtf(ss), 1e-12f);
    const float zf[4] = {e4.x*inv, e4.y*inv, e4.z*inv, e4.w*inv};
    unsigned short zb[4];
    float zz = 0.0f;
    #pragma unroll
    for (int c = 0; c < 4; ++c) {
        __hip_bfloat16 h = __float2bfloat16(zf[c]);
        union { __hip_bfloat16 h; unsigned short u; } cu; cu.h = h;
        zb[c] = cu.u;
        union { unsigned int i; float f; } cf; cf.i = (unsigned int)cu.u << 16;
        zz += cf.f * cf.f;
    }
    ushort4 pk; pk.x = zb[0]; pk.y = zb[1]; pk.z = zb[2]; pk.w = zb[3];
    ((ushort4*)(z + (size_t)row * ND))[t] = pk;

    __syncthreads();   // wred reuse
    #pragma unroll
    for (int o = 32; o > 0; o >>= 1) zz += __shfl_xor(zz, o);
    if (lane == 0) wred[wid] = zz;
    __syncthreads();
    if (t == 0) {
        mvec[row] = (wred[0] + wred[1] + wred[2] + wred[3]) * 10.0f; // /TAU
        const int* lr = labels + row * 4;
        keys[row] = ((lr[3] & 0xFF) << 24) | ((lr[0] & 0xFF) << 16) |
                    ((lr[1] & 0xFF) << 8)  |  (lr[2] & 0xFF);
    }
}

// ---------------------------------------------------------------------------
// sim tile kernel: 128x128 tile of S = Z Z^T / TAU, fused row-stats epilogue.
// Computes D[jj][ii] = Z[J0+jj] . Z[I0+ii]  (so sim ROWS i land lane-local).
// Per (coltile bj, global row i): partial {Zsum, s1,c1, s2,c2, s3,c3}.
// ---------------------------------------------------------------------------
__global__ __launch_bounds__(256) void simtile_kernel(
    const unsigned short* __restrict__ z, const float* __restrict__ mvec,
    const int* __restrict__ keys, float* __restrict__ partials)
{
    const int bi = blockIdx.x >> 5;   // sim row tile (I)
    const int bj = blockIdx.x & 31;   // sim col tile (J)
    const int I0 = bi * 128, J0 = bj * 128;
    const int tid = threadIdx.x;
    const int lane = tid & 63, wid = tid >> 6;
    const int lhi = lane >> 4, llo = lane & 15;
    const int wjj = wid >> 1, wii = wid & 1;

    __shared__ __align__(16) unsigned short ZI[128][32];
    __shared__ __align__(16) unsigned short ZJ[128][32];
    __shared__ float epi[2][128][7];
    __shared__ int   keyI[128];
    __shared__ int   keyJ[128];
    __shared__ float mI[128];

    if (tid < 128) {
        keyI[tid] = keys[I0 + tid];
        keyJ[tid] = keys[J0 + tid];
        mI[tid]   = mvec[I0 + tid];
    }

    f32x4 acc[4][4];
    #pragma unroll
    for (int m = 0; m < 4; ++m)
        #pragma unroll
        for (int n = 0; n < 4; ++n)
            acc[m][n] = (f32x4){0.f, 0.f, 0.f, 0.f};

    for (int kt = 0; kt < ND; kt += 32) {
        __syncthreads();
        #pragma unroll
        for (int c = 0; c < 2; ++c) {
            const int f  = c * 256 + tid;      // 0..511 sixteen-byte chunks
            const int r  = f >> 2;             // tile row 0..127
            const int kb = (f & 3) * 8;        // bf16 offset within 32
            const uint4 vI = *(const uint4*)(z + (size_t)(I0 + r) * ND + kt + kb);
            const uint4 vJ = *(const uint4*)(z + (size_t)(J0 + r) * ND + kt + kb);
            *(uint4*)&ZI[r][kb] = vI;
            *(uint4*)&ZJ[r][kb] = vJ;
        }
        __syncthreads();

        bf16x8 a[4], b[4];
        #pragma unroll
        for (int m = 0; m < 4; ++m)
            a[m] = *(const bf16x8*)&ZJ[wjj * 64 + m * 16 + llo][lhi * 8];
        #pragma unroll
        for (int n = 0; n < 4; ++n)
            b[n] = *(const bf16x8*)&ZI[wii * 64 + n * 16 + llo][lhi * 8];
        #pragma unroll
        for (int m = 0; m < 4; ++m)
            #pragma unroll
            for (int n = 0; n < 4; ++n)
                acc[m][n] = __builtin_amdgcn_mfma_f32_16x16x32_bf16(a[m], b[n], acc[m][n], 0, 0, 0);
    }

    // -------- epilogue: per-lane stats over its 4 sim-rows (ii), 16 cols (jj)
    float st[4][7];
    #pragma unroll
    for (int n = 0; n < 4; ++n)
        #pragma unroll
        for (int s = 0; s < 7; ++s) st[n][s] = 0.0f;

    int   kI[4]; float mIr[4]; int iiG[4];
    #pragma unroll
    for (int n = 0; n < 4; ++n) {
        const int ii = wii * 64 + n * 16 + llo;
        kI[n]  = keyI[ii];
        mIr[n] = mI[ii];
        iiG[n] = I0 + ii;
    }

    #pragma unroll
    for (int m = 0; m < 4; ++m) {
        const int jjbase = wjj * 64 + m * 16 + lhi * 4;
        #pragma unroll
        for (int r = 0; r < 4; ++r) {
            const int jj = jjbase + r;
            const int jG = J0 + jj;
            const int kj = keyJ[jj];
            #pragma unroll
            for (int n = 0; n < 4; ++n) {
                if (iiG[n] == jG) continue;              // diagonal: -inf
                const float s = acc[m][n][r] * 10.0f - mIr[n];
                const int   x = kI[n] ^ kj;
                st[n][0] += __expf(s - ((x >> 24) ? 1.0f : 0.0f)); // DIR_W penalty
                if ((x & 0xFFFF0000) == 0) {             // same dir + h0
                    st[n][1] += s; st[n][2] += 1.0f;
                    if ((x & 0xFFFFFF00) == 0) {         // + h1
                        st[n][3] += s; st[n][4] += 1.0f;
                        if (x == 0) {                    // + h2
                            st[n][5] += s; st[n][6] += 1.0f;
                        }
                    }
                }
            }
        }
    }

    // combine the 4 lane-hi groups (each holds different jj slots of same ii)
    #pragma unroll
    for (int n = 0; n < 4; ++n)
        #pragma unroll
        for (int s = 0; s < 7; ++s) {
            float v = st[n][s];
            v += __shfl_xor(v, 16);
            v += __shfl_xor(v, 32);
            st[n][s] = v;
        }

    if (lhi == 0) {
        #pragma unroll
        for (int n = 0; n < 4; ++n) {
            const int ii = wii * 64 + n * 16 + llo;
            #pragma unroll
            for (int s = 0; s < 7; ++s) epi[wjj][ii][s] = st[n][s];
        }
    }
    __syncthreads();

    if (tid < 128) {
        float* pout = partials + ((size_t)bj * NB + I0 + tid) * 8;
        #pragma unroll
        for (int s = 0; s < 7; ++s) pout[s] = epi[0][tid][s] + epi[1][tid][s];
        pout[7] = 0.0f;
    }
}

// ---------------------------------------------------------------------------
// row reduce: sum partials over 32 coltiles, compute per-row per-level values,
// reduce within block to 6 sums -> blocksums[16][8]
// ---------------------------------------------------------------------------
__global__ __launch_bounds__(256) void rowreduce_kernel(
    const float* __restrict__ partials, float* __restrict__ blocksums)
{
    const int tid = threadIdx.x;
    const int row = blockIdx.x * 256 + tid;
    const int lane = tid & 63, wid = tid >> 6;

    float a[7] = {0, 0, 0, 0, 0, 0, 0};
    for (int ct = 0; ct < 32; ++ct) {
        const float* p = partials + ((size_t)ct * NB + row) * 8;
        const float4 u = *(const float4*)p;
        const float4 v = *(const float4*)(p + 4);
        a[0] += u.x; a[1] += u.y; a[2] += u.z; a[3] += u.w;
        a[4] += v.x; a[5] += v.y; a[6] += v.z;
    }
    const float logZ = logf(fmaxf(a[0], 1.17549435e-38f));

    float vals[6];
    #pragma unroll
    for (int l = 0; l < 3; ++l) {
        const float c = a[2 + 2 * l], s = a[1 + 2 * l];
        const bool valid = c > 0.0f;
        const float pr = (s - c * logZ) / fmaxf(c, 1.0f);
        vals[2 * l]     = valid ? pr : 0.0f;
        vals[2 * l + 1] = valid ? 1.0f : 0.0f;
    }

    __shared__ float red[4][6];
    #pragma unroll
    for (int s = 0; s < 6; ++s) {
        float v = vals[s];
        #pragma unroll
        for (int o = 32; o > 0; o >>= 1) v += __shfl_xor(v, o);
        vals[s] = v;
    }
    if (lane == 0)
        #pragma unroll
        for (int s = 0; s < 6; ++s) red[wid][s] = vals[s];
    __syncthreads();
    if (tid == 0) {
        #pragma unroll
        for (int s = 0; s < 6; ++s)
            blocksums[blockIdx.x * 8 + s] = red[0][s] + red[1][s] + red[2][s] + red[3][s];
    }
}

// ---------------------------------------------------------------------------
// final: sum 16 block results, run the 3-level scalar loop
// ---------------------------------------------------------------------------
__global__ void final_kernel(const float* __restrict__ blocksums, float* __restrict__ out)
{
    if (threadIdx.x != 0) return;
    float sums[6] = {0, 0, 0, 0, 0, 0};
    for (int b = 0; b < 16; ++b)
        for (int s = 0; s < 6; ++s) sums[s] += blocksums[b * 8 + s];

    const float pen[3] = {2.0f, 1.41421356237309515f, 1.25992104989487319f};
    float total = 0.0f, max_lower = -INFINITY;
    int seen = 0;
    for (int l = 0; l < 3; ++l) {
        const float nv   = sums[2 * l + 1];
        const bool  any  = nv > 0.0f;
        const float mean = sums[2 * l] / fmaxf(nv, 1.0f);
        const float raw  = -mean;                    // TAU/TAU_BASE == 1
        const float lvl  = fmaxf(max_lower, raw);
        if (any) {
            total += lvl * pen[l];
            max_lower = fmaxf(max_lower, lvl);
            seen++;
        }
    }
    out[0] = total / (float)(seen > 0 ? seen : 1);
}

// ---------------------------------------------------------------------------
extern "C" void kernel_launch(void* const* d_in, const int* in_sizes, int n_in,
                              void* d_out, int out_size, void* d_ws, size_t ws_size,
                              hipStream_t stream)
{
    const float* emb    = (const float*)d_in[0];
    const int*   labels = (const int*)d_in[1];
    float*       out    = (float*)d_out;
    char*        ws     = (char*)d_ws;

    // ws layout
    unsigned short* z        = (unsigned short*)(ws);                 // 8388608 B
    float*          mvec     = (float*)(ws + 8388608);                // 16384 B
    int*            keys     = (int*)(ws + 8404992);                  // 16384 B
    float*          partials = (float*)(ws + 8421376);                // 4194304 B
    float*          bsums    = (float*)(ws + 12615680);               // 512 B

    prep_kernel<<<NB, 256, 0, stream>>>(emb, labels, z, mvec, keys);
    simtile_kernel<<<1024, 256, 0, stream>>>(z, mvec, keys, partials);
    rowreduce_kernel<<<NB / 256, 256, 0, stream>>>(partials, bsums);
    final_kernel<<<1, 64, 0, stream>>>(bsums, out);
}